// Round 17
// baseline (442.122 us; speedup 1.0000x reference)
//
#include <hip/hip_runtime.h>
#include <math.h>

#define NN 50000
#define NE 800000

typedef __attribute__((ext_vector_type(8))) short bh8;      // 8 bf16 = 4 VGPR (MFMA A/B frag)
typedef __attribute__((ext_vector_type(4))) float fx4;      // MFMA C/D frag
typedef __attribute__((ext_vector_type(4))) unsigned bu4;   // 4 u32 = 8 packed bf16

__device__ __forceinline__ short f2b(float x) {
    union { float f; unsigned u; } a; a.f = x;
    unsigned r = a.u + 0x7FFF + ((a.u >> 16) & 1);   // round-to-nearest-even
    return (short)(r >> 16);
}
__device__ __forceinline__ float b2f(short s) {
    union { unsigned u; float f; } a; a.u = ((unsigned)(unsigned short)s) << 16;
    return a.f;
}
__device__ __forceinline__ float sigm(float x) { return 1.f / (1.f + __expf(-x)); }

__device__ __forceinline__ unsigned cvtpk(float a, float b) {
    unsigned r;
    asm("v_cvt_pk_bf16_f32 %0, %1, %2" : "=v"(r) : "v"(a), "v"(b));
    return r;
}

// split 8 f32 into hi-bf16 pack + lo-bf16 pack (lo = x - f32(hi))
__device__ __forceinline__ void split8(const float v[8], bh8& hi, bh8& lo) {
    union { bu4 u; bh8 h; } H, L;
#pragma unroll
    for (int j = 0; j < 4; j++) {
        unsigned p = cvtpk(v[2 * j], v[2 * j + 1]);
        H.u[j] = p;
        union { unsigned u; float f; } e0, e1;
        e0.u = p << 16;
        e1.u = p & 0xFFFF0000u;
        L.u[j] = cvtpk(v[2 * j] - e0.f, v[2 * j + 1] - e1.f);
    }
    hi = H.h; lo = L.h;
}

#define MFMA3(acc, Ah, Al, Bh, Bl)                                            \
    acc = __builtin_amdgcn_mfma_f32_16x16x32_bf16(Ah, Bh, acc, 0, 0, 0);      \
    acc = __builtin_amdgcn_mfma_f32_16x16x32_bf16(Al, Bh, acc, 0, 0, 0);      \
    acc = __builtin_amdgcn_mfma_f32_16x16x32_bf16(Ah, Bl, acc, 0, 0, 0);

// bijective XCD-chunked swizzle (m204)
__device__ __forceinline__ int xcd_swz(int bid, int nwg) {
    int xcd = bid & 7, bidx = bid >> 3;
    int q = nwg >> 3, r = nwg & 7;
    return (xcd < r ? xcd * (q + 1) : r * (q + 1) + (xcd - r) * q) + bidx;
}

// ---------------- fused prep (+ CSR cnt/cur zeroing) ----------------
__global__ __launch_bounds__(256) void prep_all(
    const float* __restrict__ W1,
    const float* __restrict__ W2, const float* __restrict__ W3,
    const float* __restrict__ Wih, const float* __restrict__ Whh,
    float* __restrict__ wf,
    short* __restrict__ W2tB, short* __restrict__ W3tB,
    short* __restrict__ WihT_hi, short* __restrict__ WihT_lo,
    short* __restrict__ WhhT_hi, short* __restrict__ WhhT_lo,
    short* __restrict__ W1aT_hi, short* __restrict__ W1aT_lo,
    short* __restrict__ W1bT_hi, short* __restrict__ W1bT_lo,
    int* __restrict__ cnt, int* __restrict__ cur)
{
    int i = blockIdx.x * 256 + threadIdx.x;
    if (i < NN) { cnt[i] = 0; cur[i] = 0; }
    if (i < 64) {
        wf[i]       = W1[64 * 64 + i]  - W1[65 * 64 + i];
        wf[64 + i]  = W1[133 * 64 + i] - W1[132 * 64 + i];
        wf[128 + i] = W1[66 * 64 + i] - W1[67 * 64 + i]
                    - W1[134 * 64 + i] + W1[135 * 64 + i];
    }
    if (i < 4096) {
        int c = i >> 6, k = i & 63;
        W2tB[i] = f2b(W2[k * 64 + c]);
        W3tB[i] = f2b(W3[k * 64 + c]);
        float v = W1[k * 64 + c];
        short h = f2b(v);
        W1aT_hi[i] = h; W1aT_lo[i] = f2b(v - b2f(h));
        v = W1[(68 + k) * 64 + c];
        h = f2b(v);
        W1bT_hi[i] = h; W1bT_lo[i] = f2b(v - b2f(h));
    }
    if (i < 12288) {
        int c = i >> 6, k = i & 63;
        float v = Wih[(size_t)k * 192 + c];
        short h = f2b(v);
        WihT_hi[i] = h; WihT_lo[i] = f2b(v - b2f(h));
        v = Whh[(size_t)k * 192 + c];
        h = f2b(v);
        WhhT_hi[i] = h; WhhT_lo[i] = f2b(v - b2f(h));
    }
}

// init state/agg + CSR count (cnt zeroed in prep_all, which runs earlier on stream)
__global__ __launch_bounds__(256) void init_state(
    const float* __restrict__ b, const float* __restrict__ W_in,
    const float* __restrict__ b_in, const int* __restrict__ mn,
    float* __restrict__ state, float* __restrict__ agg0, float* __restrict__ agg1,
    int* __restrict__ cnt)
{
    int idx = blockIdx.x * 256 + threadIdx.x;
    if (idx >= NN * 64) return;
    int n = idx >> 6, j = idx & 63;
    state[idx] = b[n] * (W_in[j] - W_in[64 + j]) + b_in[j];
    agg0[idx] = 0.f;
    agg1[idx] = 0.f;
    if (idx < NE) atomicAdd(&cnt[mn[2 * idx + 1]], 1);
}

// ---------------- CSR scan + scatter ----------------
__global__ __launch_bounds__(256) void scan_block(const int* __restrict__ cnt,
                                                  int* __restrict__ base, int* __restrict__ bsum)
{
    __shared__ int s[256];
    int i = blockIdx.x * 256 + threadIdx.x;
    int v = (i < NN) ? cnt[i] : 0;
    s[threadIdx.x] = v;
    __syncthreads();
    for (int off = 1; off < 256; off <<= 1) {
        int t = (threadIdx.x >= off) ? s[threadIdx.x - off] : 0;
        __syncthreads();
        s[threadIdx.x] += t;
        __syncthreads();
    }
    if (i < NN) base[i] = s[threadIdx.x] - v;
    if (threadIdx.x == 255) bsum[blockIdx.x] = s[255];
}

__global__ __launch_bounds__(256) void scan_top(int* __restrict__ bsum, int nb)
{
    __shared__ int s[256];
    int t = threadIdx.x;
    int v = (t < nb) ? bsum[t] : 0;
    s[t] = v;
    __syncthreads();
    for (int off = 1; off < 256; off <<= 1) {
        int u = (t >= off) ? s[t - off] : 0;
        __syncthreads();
        s[t] += u;
        __syncthreads();
    }
    if (t < nb) bsum[t] = s[t] - v;
}

// AoS scatter: one 16B store per edge (ein, eout, J_bits, 0)
__global__ __launch_bounds__(256) void csr_scatter_perm(const int* __restrict__ mn,
    const float* __restrict__ Jm,
    const int* __restrict__ base, const int* __restrict__ bsum, int* __restrict__ cur,
    int4* __restrict__ edata)
{
    int e = blockIdx.x * 256 + threadIdx.x;
    if (e < NE) {
        int n = mn[2 * e + 1];
        int p = base[n] + bsum[n >> 8] + atomicAdd(&cur[n], 1);
        edata[p] = make_int4(mn[2 * e], n, __float_as_int(Jm[e]), 0);
    }
}

// ---------------- node_proj via MFMA (3-term split; weights in LDS) ----------------
__global__ __launch_bounds__(256, 4) void node_proj_mfma(
    const float* __restrict__ state, const float* __restrict__ bb,
    const short* __restrict__ W1aT_hi, const short* __restrict__ W1aT_lo,
    const short* __restrict__ W1bT_hi, const short* __restrict__ W1bT_lo,
    const float* __restrict__ wf, const float* __restrict__ b1,
    float* __restrict__ Pin, float* __restrict__ Pout)
{
    __shared__ float xh[64][68];
    __shared__ short wH[64][72];
    __shared__ short wL[64][72];
    __shared__ float sb[64];

    int tid = threadIdx.x;
    int wg = xcd_swz(blockIdx.x, gridDim.x);
    int ct = wg & 1;
    int n0 = (wg >> 1) * 64;

    const short* srcH = ct ? W1bT_hi : W1aT_hi;
    const short* srcL = ct ? W1bT_lo : W1aT_lo;
    float* P = ct ? Pout : Pin;

    {
        int row = tid >> 2, cb = (tid & 3) * 16;
        int n = n0 + row;
        bool ok = (n < NN);
#pragma unroll
        for (int q = 0; q < 4; q++) {
            float4 v = ok ? *(const float4*)&state[(size_t)n * 64 + cb + 4 * q]
                          : make_float4(0.f, 0.f, 0.f, 0.f);
            *(float4*)&xh[row][cb + 4 * q] = v;
        }
        *(bh8*)&wH[row][cb]     = *(const bh8*)&srcH[row * 64 + cb];
        *(bh8*)&wH[row][cb + 8] = *(const bh8*)&srcH[row * 64 + cb + 8];
        *(bh8*)&wL[row][cb]     = *(const bh8*)&srcL[row * 64 + cb];
        *(bh8*)&wL[row][cb + 8] = *(const bh8*)&srcL[row * 64 + cb + 8];
        if (tid < 64) sb[tid] = (n0 + tid < NN) ? bb[n0 + tid] : 0.f;
    }
    __syncthreads();

    int w = tid >> 6, l = tid & 63, lr = l & 15, lg = l >> 4;

    bh8 Sh1, Sl1, Sh2, Sl2;
    {
        float v[8];
        *(float4*)&v[0] = *(const float4*)&xh[16 * w + lr][8 * lg];
        *(float4*)&v[4] = *(const float4*)&xh[16 * w + lr][8 * lg + 4];
        split8(v, Sh1, Sl1);
        *(float4*)&v[0] = *(const float4*)&xh[16 * w + lr][8 * lg + 32];
        *(float4*)&v[4] = *(const float4*)&xh[16 * w + lr][8 * lg + 36];
        split8(v, Sh2, Sl2);
    }

#pragma unroll
    for (int c4 = 0; c4 < 4; c4++) {
        int brow = 16 * c4 + lr;
        bh8 Bh1 = *(const bh8*)&wH[brow][8 * lg];
        bh8 Bl1 = *(const bh8*)&wL[brow][8 * lg];
        bh8 Bh2 = *(const bh8*)&wH[brow][8 * lg + 32];
        bh8 Bl2 = *(const bh8*)&wL[brow][8 * lg + 32];
        fx4 acc = {0.f, 0.f, 0.f, 0.f};
        MFMA3(acc, Sh1, Sl1, Bh1, Bl1)
        MFMA3(acc, Sh2, Sl2, Bh2, Bl2)

        int c = 16 * c4 + lr;
        float F = wf[ct * 64 + c];
        float Bi = ct ? 0.f : b1[c];
#pragma unroll
        for (int r = 0; r < 4; r++) {
            int row = 16 * w + 4 * lg + r;
            int n = n0 + row;
            if (n < NN) P[(size_t)n * 64 + c] = acc[r] + sb[row] * F + Bi;
        }
    }
}

// ---------------- edge MLP + fused segment-sum ----------------
// 6 blocks/CU; per-wave band staging: wave w gathers edges [16w,16w+16) and flows
// straight into GEMM2 (within-wave LDS ordering; no block barrier on the gather).
__global__ __launch_bounds__(256, 6) void edge_msg_mfma(
    const int4* __restrict__ edata,
    const float* __restrict__ Pin, const float* __restrict__ Pout,
    const float* __restrict__ wf,
    const short* __restrict__ W2tB, const float* __restrict__ b2,
    const short* __restrict__ W3tB, const float* __restrict__ b3,
    float* __restrict__ agg)
{
    __shared__ float h1f[64][68];   // h1, then h2 (band-private), then tband alias
    __shared__ short w23[64][72];   // W2^T, then restaged with W3^T
    __shared__ int   seo[64];

    float* tband = &h1f[0][0];      // 4*64 floats alias (h1f dead after GEMM3 reads)

    int tid = threadIdx.x;
    int wg = xcd_swz(blockIdx.x, gridDim.x);
    int p0 = wg * 64;

    int srow = tid >> 2, scb = (tid & 3) * 16;

    {   // phase 0: seo + W2 (fenced by one barrier)
        if (tid < 64) seo[tid] = edata[p0 + tid].y;
        *(bh8*)&w23[srow][scb]     = *(const bh8*)&W2tB[srow * 64 + scb];
        *(bh8*)&w23[srow][scb + 8] = *(const bh8*)&W2tB[srow * 64 + scb + 8];
    }
    __syncthreads();

    int w = tid >> 6, l = tid & 63;
    int lr = l & 15, lg = l >> 4;

    {   // phase 1: per-wave h1 staging (own band; 4 lanes per edge-row, coalesced)
        int e = 16 * w + (l >> 2), kb = (l & 3) * 16;
        int4 ed = edata[p0 + e];
        int a = ed.x, o = ed.y;
        float J = __int_as_float(ed.z);
#pragma unroll
        for (int q = 0; q < 4; q++) {
            float4 va = *(const float4*)&Pin[(size_t)a * 64 + kb + 4 * q];
            float4 vo = *(const float4*)&Pout[(size_t)o * 64 + kb + 4 * q];
            float4 vc = *(const float4*)&wf[128 + kb + 4 * q];
            float4 r;
            r.x = fmaxf(va.x + vo.x + J * vc.x, 0.f);
            r.y = fmaxf(va.y + vo.y + J * vc.y, 0.f);
            r.z = fmaxf(va.z + vo.z + J * vc.z, 0.f);
            r.w = fmaxf(va.w + vo.w + J * vc.w, 0.f);
            *(float4*)&h1f[e][kb + 4 * q] = r;
        }
    }
    // no barrier: GEMM2 reads only this wave's band rows (in-wave LDS order)

    float b2v[4], b3v[4];
#pragma unroll
    for (int ct = 0; ct < 4; ct++) { b2v[ct] = b2[ct * 16 + lr]; b3v[ct] = b3[ct * 16 + lr]; }

    // ---- GEMM2: h2 = relu(h1 @ W2 + b2); h2 -> h1f (own band) ----
    {
        float va[8], vb[8];
        *(float4*)&va[0] = *(const float4*)&h1f[16 * w + lr][lg * 8];
        *(float4*)&va[4] = *(const float4*)&h1f[16 * w + lr][lg * 8 + 4];
        *(float4*)&vb[0] = *(const float4*)&h1f[16 * w + lr][lg * 8 + 32];
        *(float4*)&vb[4] = *(const float4*)&h1f[16 * w + lr][lg * 8 + 36];
        bh8 Ahi1, Alo1, Ahi2, Alo2;
        split8(va, Ahi1, Alo1);
        split8(vb, Ahi2, Alo2);
#pragma unroll
        for (int ct = 0; ct < 4; ct++) {
            bh8 B1 = *(const bh8*)&w23[16 * ct + lr][lg * 8];
            bh8 B2 = *(const bh8*)&w23[16 * ct + lr][lg * 8 + 32];
            fx4 acc = {0.f, 0.f, 0.f, 0.f};
            acc = __builtin_amdgcn_mfma_f32_16x16x32_bf16(Ahi1, B1, acc, 0, 0, 0);
            acc = __builtin_amdgcn_mfma_f32_16x16x32_bf16(Alo1, B1, acc, 0, 0, 0);
            acc = __builtin_amdgcn_mfma_f32_16x16x32_bf16(Ahi2, B2, acc, 0, 0, 0);
            acc = __builtin_amdgcn_mfma_f32_16x16x32_bf16(Alo2, B2, acc, 0, 0, 0);
#pragma unroll
            for (int r = 0; r < 4; r++)
                h1f[16 * w + 4 * lg + r][16 * ct + lr] = fmaxf(acc[r] + b2v[ct], 0.f);
        }
    }
    __syncthreads();   // all waves' W2 reads done

    {   // restage w23 <- W3
        *(bh8*)&w23[srow][scb]     = *(const bh8*)&W3tB[srow * 64 + scb];
        *(bh8*)&w23[srow][scb + 8] = *(const bh8*)&W3tB[srow * 64 + scb + 8];
    }
    __syncthreads();

    // ---- GEMM3: m = h2 @ W3 + b3 -> registers ----
    fx4 macc[4];
    {
        float va[8], vb[8];
        *(float4*)&va[0] = *(const float4*)&h1f[16 * w + lr][lg * 8];
        *(float4*)&va[4] = *(const float4*)&h1f[16 * w + lr][lg * 8 + 4];
        *(float4*)&vb[0] = *(const float4*)&h1f[16 * w + lr][lg * 8 + 32];
        *(float4*)&vb[4] = *(const float4*)&h1f[16 * w + lr][lg * 8 + 36];
        bh8 Chi1, Clo1, Chi2, Clo2;
        split8(va, Chi1, Clo1);
        split8(vb, Chi2, Clo2);
#pragma unroll
        for (int ct = 0; ct < 4; ct++) {
            bh8 B1 = *(const bh8*)&w23[16 * ct + lr][lg * 8];
            bh8 B2 = *(const bh8*)&w23[16 * ct + lr][lg * 8 + 32];
            fx4 acc = {0.f, 0.f, 0.f, 0.f};
            acc = __builtin_amdgcn_mfma_f32_16x16x32_bf16(Chi1, B1, acc, 0, 0, 0);
            acc = __builtin_amdgcn_mfma_f32_16x16x32_bf16(Clo1, B1, acc, 0, 0, 0);
            acc = __builtin_amdgcn_mfma_f32_16x16x32_bf16(Chi2, B2, acc, 0, 0, 0);
            acc = __builtin_amdgcn_mfma_f32_16x16x32_bf16(Clo2, B2, acc, 0, 0, 0);
#pragma unroll
            for (int r = 0; r < 4; r++) acc[r] += b3v[ct];
            macc[ct] = acc;
        }
    }

    // ---- segmented scan ----
    int rowb = 16 * w + 4 * lg;
    int s0 = seo[rowb], s1 = seo[rowb + 1], s2 = seo[rowb + 2], s3 = seo[rowb + 3];

#pragma unroll
    for (int ct = 0; ct < 4; ct++) {
        if (s1 == s0) macc[ct][1] += macc[ct][0];
        if (s2 == s1) macc[ct][2] += macc[ct][1];
        if (s3 == s2) macc[ct][3] += macc[ct][2];
    }

    float c0[4], c1[4], c2[4];
#pragma unroll
    for (int ct = 0; ct < 4; ct++) {
        c0[ct] = __shfl(macc[ct][3], lr, 64);
        c1[ct] = __shfl(macc[ct][3], lr + 16, 64);
        c2[ct] = __shfl(macc[ct][3], lr + 32, 64);
    }
    {
        int k0 = seo[16 * w + 3], k1 = seo[16 * w + 7], k2 = seo[16 * w + 11];
        float cy[4] = {0.f, 0.f, 0.f, 0.f};
        bool m0 = (lg >= 1) && (k0 == s0);
        bool m1 = (lg >= 2) && (k1 == s0);
        bool m2 = (lg >= 3) && (k2 == s0);
#pragma unroll
        for (int ct = 0; ct < 4; ct++) {
            if (m0) cy[ct] += c0[ct];
            if (m1) cy[ct] += c1[ct];
            if (m2) cy[ct] += c2[ct];
        }
#pragma unroll
        for (int ct = 0; ct < 4; ct++) {
            macc[ct][0] += cy[ct];
            if (s1 == s0) macc[ct][1] += cy[ct];
            if (s2 == s0) macc[ct][2] += cy[ct];
            if (s3 == s0) macc[ct][3] += cy[ct];
        }
    }

    __syncthreads();   // all GEMM3 h1f reads done before tband (alias) writes
    if (lg == 3) {
#pragma unroll
        for (int ct = 0; ct < 4; ct++) tband[w * 64 + 16 * ct + lr] = macc[ct][3];
    }
    __syncthreads();
    {
        int bkey = seo[16 * w];
        int t0 = seo[15], t1 = seo[31], t2 = seo[47];
        float bc[4] = {0.f, 0.f, 0.f, 0.f};
        bool m0 = (w >= 1) && (t0 == bkey);
        bool m1 = (w >= 2) && (t1 == bkey);
        bool m2 = (w >= 3) && (t2 == bkey);
#pragma unroll
        for (int ct = 0; ct < 4; ct++) {
            if (m0) bc[ct] += tband[0 * 64 + 16 * ct + lr];
            if (m1) bc[ct] += tband[1 * 64 + 16 * ct + lr];
            if (m2) bc[ct] += tband[2 * 64 + 16 * ct + lr];
        }
#pragma unroll
        for (int ct = 0; ct < 4; ct++) {
            if (s0 == bkey) macc[ct][0] += bc[ct];
            if (s1 == bkey) macc[ct][1] += bc[ct];
            if (s2 == bkey) macc[ct][2] += bc[ct];
            if (s3 == bkey) macc[ct][3] += bc[ct];
        }
    }

    {   // emit tails
        int nh = seo[0], nt = seo[63];
        int sr[4] = { s0, s1, s2, s3 };
#pragma unroll
        for (int r = 0; r < 4; r++) {
            int p = rowb + r;
            int n = sr[r];
            bool tail = (p == 63) || (seo[p + 1] != n);
            if (tail) {
                float* ar = agg + (size_t)n * 64;
                if (n != nh && n != nt) {
                    ar[lr]      = macc[0][r];
                    ar[16 + lr] = macc[1][r];
                    ar[32 + lr] = macc[2][r];
                    ar[48 + lr] = macc[3][r];
                } else {
                    atomicAdd(&ar[lr],      macc[0][r]);
                    atomicAdd(&ar[16 + lr], macc[1][r]);
                    atomicAdd(&ar[32 + lr], macc[2][r]);
                    atomicAdd(&ar[48 + lr], macc[3][r]);
                }
            }
        }
    }
}

// ---------------- GRU via MFMA, q-split; A-frags direct from global; 5 blocks/CU ----------------
__global__ __launch_bounds__(256, 5) void gru_mfma(
    const float* __restrict__ agg, const float* __restrict__ state,
    const short* __restrict__ WihT_hi, const short* __restrict__ WihT_lo,
    const short* __restrict__ WhhT_hi, const short* __restrict__ WhhT_lo,
    const float* __restrict__ bih, const float* __restrict__ bhh,
    float* __restrict__ stateNext, float* __restrict__ aggNext)
{
    __shared__ short wiH[48][72];
    __shared__ short wiL[48][72];
    __shared__ short whH[48][72];
    __shared__ short whL[48][72];

    int tid = threadIdx.x;
    int wg = xcd_swz(blockIdx.x, gridDim.x);
    int tile = wg >> 2, q = wg & 3;
    int n0 = tile * 64;
    int w = tid >> 6, l = tid & 63, lr = l & 15, lg = l >> 4;

    int arow = 16 * w + lr;
    size_t abase = (size_t)(n0 + arow) * 64;

    bh8 Agh1, Agl1, Agh2, Agl2, Ash1, Asl1, Ash2, Asl2;
    {
        float v[8];
        *(float4*)&v[0] = *(const float4*)&agg[abase + 8 * lg];
        *(float4*)&v[4] = *(const float4*)&agg[abase + 8 * lg + 4];
        split8(v, Agh1, Agl1);
        *(float4*)&v[0] = *(const float4*)&agg[abase + 8 * lg + 32];
        *(float4*)&v[4] = *(const float4*)&agg[abase + 8 * lg + 36];
        split8(v, Agh2, Agl2);
        *(float4*)&v[0] = *(const float4*)&state[abase + 8 * lg];
        *(float4*)&v[4] = *(const float4*)&state[abase + 8 * lg + 4];
        split8(v, Ash1, Asl1);
        *(float4*)&v[0] = *(const float4*)&state[abase + 8 * lg + 32];
        *(float4*)&v[4] = *(const float4*)&state[abase + 8 * lg + 36];
        split8(v, Ash2, Asl2);
    }

    {   // stage weights + zero aggNext (q==0)
        const short* src = (w == 0) ? WihT_hi : (w == 1) ? WihT_lo
                         : (w == 2) ? WhhT_hi : WhhT_lo;
        short (*dst)[72] = (w == 0) ? wiH : (w == 1) ? wiL : (w == 2) ? whH : whL;
#pragma unroll
        for (int it = 0; it < 6; it++) {
            int idx = it * 64 + l;
            int row2 = idx >> 3, ch = idx & 7;
            int g = row2 >> 4, i = row2 & 15;
            int gcol = g * 64 + q * 16 + i;
            *(bh8*)&dst[row2][ch * 8] = *(const bh8*)&src[(size_t)gcol * 64 + ch * 8];
        }
        if (q == 0) {
            int row = tid >> 2, cb = (tid & 3) * 16;
            int n = n0 + row;
            if (n < NN) {
#pragma unroll
                for (int qq = 0; qq < 4; qq++)
                    *(float4*)&aggNext[(size_t)n * 64 + cb + 4 * qq] =
                        make_float4(0.f, 0.f, 0.f, 0.f);
            }
        }
    }
    __syncthreads();

    fx4 giT[3], ghT[3];
#pragma unroll
    for (int g = 0; g < 3; g++) {
        int brow = g * 16 + lr;
        {
            bh8 Bh1 = *(const bh8*)&wiH[brow][8 * lg];
            bh8 Bl1 = *(const bh8*)&wiL[brow][8 * lg];
            bh8 Bh2 = *(const bh8*)&wiH[brow][8 * lg + 32];
            bh8 Bl2 = *(const bh8*)&wiL[brow][8 * lg + 32];
            fx4 acc = {0.f, 0.f, 0.f, 0.f};
            MFMA3(acc, Agh1, Agl1, Bh1, Bl1)
            MFMA3(acc, Agh2, Agl2, Bh2, Bl2)
            giT[g] = acc;
        }
        {
            bh8 Bh1 = *(const bh8*)&whH[brow][8 * lg];
            bh8 Bl1 = *(const bh8*)&whL[brow][8 * lg];
            bh8 Bh2 = *(const bh8*)&whH[brow][8 * lg + 32];
            bh8 Bl2 = *(const bh8*)&whL[brow][8 * lg + 32];
            fx4 acc = {0.f, 0.f, 0.f, 0.f};
            MFMA3(acc, Ash1, Asl1, Bh1, Bl1)
            MFMA3(acc, Ash2, Asl2, Bh2, Bl2)
            ghT[g] = acc;
        }
    }

    {
        int c = q * 16 + lr;
        float bir = bih[c], biz = bih[64 + c], bin = bih[128 + c];
        float bhr = bhh[c], bhz = bhh[64 + c], bhn = bhh[128 + c];
#pragma unroll
        for (int r = 0; r < 4; r++) {
            int row = 16 * w + 4 * lg + r;
            int n = n0 + row;
            if (n < NN) {
                float rg = sigm(giT[0][r] + bir + ghT[0][r] + bhr);
                float zg = sigm(giT[1][r] + biz + ghT[1][r] + bhz);
                float ng = tanhf(giT[2][r] + bin + rg * (ghT[2][r] + bhn));
                float hold = state[(size_t)n * 64 + c];
                stateNext[(size_t)n * 64 + c] = (1.f - zg) * ng + zg * hold;
            }
        }
    }
}

__global__ __launch_bounds__(256) void out_proj(
    const float* __restrict__ state, const float* __restrict__ Wout,
    const float* __restrict__ bout, float* __restrict__ out)
{
    int n = blockIdx.x * 256 + threadIdx.x;
    if (n >= NN) return;
    float a0 = bout[0], a1 = bout[1];
    const float4* sr = (const float4*)(state + (size_t)n * 64);
#pragma unroll
    for (int t = 0; t < 16; t++) {
        float4 v = sr[t];
        a0 += v.x * Wout[2 * (4 * t + 0)] + v.y * Wout[2 * (4 * t + 1)]
            + v.z * Wout[2 * (4 * t + 2)] + v.w * Wout[2 * (4 * t + 3)];
        a1 += v.x * Wout[2 * (4 * t + 0) + 1] + v.y * Wout[2 * (4 * t + 1) + 1]
            + v.z * Wout[2 * (4 * t + 2) + 1] + v.w * Wout[2 * (4 * t + 3) + 1];
    }
    out[2 * n] = a0;
    out[2 * n + 1] = a1;
}

extern "C" void kernel_launch(void* const* d_in, const int* in_sizes, int n_in,
                              void* d_out, int out_size, void* d_ws, size_t ws_size,
                              hipStream_t stream)
{
    const int*   msg_node = (const int*)  d_in[0];
    const float* J_msg    = (const float*)d_in[1];
    const float* b        = (const float*)d_in[2];
    const float* W_in     = (const float*)d_in[4];
    const float* b_in     = (const float*)d_in[5];
    const float* W1       = (const float*)d_in[6];
    const float* b1       = (const float*)d_in[7];
    const float* W2       = (const float*)d_in[8];
    const float* b2       = (const float*)d_in[9];
    const float* W3       = (const float*)d_in[10];
    const float* b3       = (const float*)d_in[11];
    const float* W_ih     = (const float*)d_in[12];
    const float* b_ih     = (const float*)d_in[13];
    const float* W_hh     = (const float*)d_in[14];
    const float* b_hh     = (const float*)d_in[15];
    const float* W_out    = (const float*)d_in[16];
    const float* b_out    = (const float*)d_in[17];

    float* f      = (float*)d_ws;
    float* state0 = f;                                  // NN*64
    float* state1 = state0 + (size_t)NN * 64;           // NN*64
    float* agg0   = state1 + (size_t)NN * 64;           // NN*64
    float* agg1   = agg0   + (size_t)NN * 64;           // NN*64
    float* Pin    = agg1   + (size_t)NN * 64;           // NN*64
    float* Pout   = Pin    + (size_t)NN * 64;           // NN*64
    float* wf     = Pout   + (size_t)NN * 64;           // 192
    int*   cbase  = (int*)(wf + 192);                   // NN
    int*   ccnt   = cbase + NN;                         // NN
    int*   ccur   = ccnt + NN;                          // NN
    int*   cbsum  = ccur + NN;                          // 512
    short* W2tB   = (short*)(cbsum + 512);              // 4096
    short* W3tB   = W2tB + 4096;                        // 4096
    short* WihT_hi = W3tB + 4096;                       // 12288
    short* WihT_lo = WihT_hi + 12288;
    short* WhhT_hi = WihT_lo + 12288;
    short* WhhT_lo = WhhT_hi + 12288;
    short* W1aT_hi = WhhT_lo + 12288;                   // 4096
    short* W1aT_lo = W1aT_hi + 4096;
    short* W1bT_hi = W1aT_lo + 4096;
    short* W1bT_lo = W1bT_hi + 4096;
    size_t off = ((size_t)((char*)(W1bT_lo + 4096) - (char*)d_ws) + 15) & ~(size_t)15;
    int4*  edata = (int4*)((char*)d_ws + off);          // NE int4

    float* stateBuf[2] = { state0, state1 };
    float* aggBuf[2]   = { agg0, agg1 };
    float* out = (float*)d_out;

    prep_all<<<(NN + 255) / 256, 256, 0, stream>>>(W1, W2, W3, W_ih, W_hh, wf,
                                                   W2tB, W3tB,
                                                   WihT_hi, WihT_lo, WhhT_hi, WhhT_lo,
                                                   W1aT_hi, W1aT_lo, W1bT_hi, W1bT_lo,
                                                   ccnt, ccur);
    init_state<<<(NN * 64 + 255) / 256, 256, 0, stream>>>(b, W_in, b_in, msg_node,
                                                          state0, agg0, agg1, ccnt);

    scan_block<<<(NN + 255) / 256, 256, 0, stream>>>(ccnt, cbase, cbsum);
    scan_top<<<1, 256, 0, stream>>>(cbsum, (NN + 255) / 256);
    csr_scatter_perm<<<(NE + 255) / 256, 256, 0, stream>>>(msg_node, J_msg,
                                                           cbase, cbsum, ccur,
                                                           edata);

    int ntile = (NN + 63) / 64;
    for (int p = 0; p < 3; p++) {
        float* sc = stateBuf[p & 1];
        float* sn = stateBuf[(p + 1) & 1];
        float* ac = aggBuf[p & 1];
        float* an = aggBuf[(p + 1) & 1];
        node_proj_mfma<<<ntile * 2, 256, 0, stream>>>(sc, b,
                                                      W1aT_hi, W1aT_lo, W1bT_hi, W1bT_lo,
                                                      wf, b1, Pin, Pout);
        edge_msg_mfma<<<NE / 64, 256, 0, stream>>>(edata, Pin, Pout, wf,
                                                   W2tB, b2, W3tB, b3, ac);
        gru_mfma<<<ntile * 4, 256, 0, stream>>>(ac, sc,
                                                WihT_hi, WihT_lo, WhhT_hi, WhhT_lo,
                                                b_ih, b_hh, sn, an);
    }
    out_proj<<<(NN + 255) / 256, 256, 0, stream>>>(stateBuf[1], W_out, b_out, out);
}

// Round 18
// 418.851 us; speedup vs baseline: 1.0556x; 1.0556x over previous
//
#include <hip/hip_runtime.h>
#include <math.h>

#define NN 50000
#define NE 800000

typedef __attribute__((ext_vector_type(8))) short bh8;      // 8 bf16 = 4 VGPR (MFMA A/B frag)
typedef __attribute__((ext_vector_type(4))) float fx4;      // MFMA C/D frag
typedef __attribute__((ext_vector_type(4))) unsigned bu4;   // 4 u32 = 8 packed bf16

__device__ __forceinline__ short f2b(float x) {
    union { float f; unsigned u; } a; a.f = x;
    unsigned r = a.u + 0x7FFF + ((a.u >> 16) & 1);   // round-to-nearest-even
    return (short)(r >> 16);
}
__device__ __forceinline__ float b2f(short s) {
    union { unsigned u; float f; } a; a.u = ((unsigned)(unsigned short)s) << 16;
    return a.f;
}
__device__ __forceinline__ float sigm(float x) { return 1.f / (1.f + __expf(-x)); }

__device__ __forceinline__ unsigned cvtpk(float a, float b) {
    unsigned r;
    asm("v_cvt_pk_bf16_f32 %0, %1, %2" : "=v"(r) : "v"(a), "v"(b));
    return r;
}

// split 8 f32 into hi-bf16 pack + lo-bf16 pack (lo = x - f32(hi))
__device__ __forceinline__ void split8(const float v[8], bh8& hi, bh8& lo) {
    union { bu4 u; bh8 h; } H, L;
#pragma unroll
    for (int j = 0; j < 4; j++) {
        unsigned p = cvtpk(v[2 * j], v[2 * j + 1]);
        H.u[j] = p;
        union { unsigned u; float f; } e0, e1;
        e0.u = p << 16;
        e1.u = p & 0xFFFF0000u;
        L.u[j] = cvtpk(v[2 * j] - e0.f, v[2 * j + 1] - e1.f);
    }
    hi = H.h; lo = L.h;
}

#define MFMA3(acc, Ah, Al, Bh, Bl)                                            \
    acc = __builtin_amdgcn_mfma_f32_16x16x32_bf16(Ah, Bh, acc, 0, 0, 0);      \
    acc = __builtin_amdgcn_mfma_f32_16x16x32_bf16(Al, Bh, acc, 0, 0, 0);      \
    acc = __builtin_amdgcn_mfma_f32_16x16x32_bf16(Ah, Bl, acc, 0, 0, 0);

// bijective XCD-chunked swizzle (m204)
__device__ __forceinline__ int xcd_swz(int bid, int nwg) {
    int xcd = bid & 7, bidx = bid >> 3;
    int q = nwg >> 3, r = nwg & 7;
    return (xcd < r ? xcd * (q + 1) : r * (q + 1) + (xcd - r) * q) + bidx;
}

// ---------------- fused prep (+ CSR cnt/cur zeroing) ----------------
__global__ __launch_bounds__(256) void prep_all(
    const float* __restrict__ W1,
    const float* __restrict__ W2, const float* __restrict__ W3,
    const float* __restrict__ Wih, const float* __restrict__ Whh,
    float* __restrict__ wf,
    short* __restrict__ W2tB, short* __restrict__ W3tB,
    short* __restrict__ WihT_hi, short* __restrict__ WihT_lo,
    short* __restrict__ WhhT_hi, short* __restrict__ WhhT_lo,
    short* __restrict__ W1aT_hi, short* __restrict__ W1aT_lo,
    short* __restrict__ W1bT_hi, short* __restrict__ W1bT_lo,
    int* __restrict__ cnt, int* __restrict__ cur)
{
    int i = blockIdx.x * 256 + threadIdx.x;
    if (i < NN) { cnt[i] = 0; cur[i] = 0; }
    if (i < 64) {
        wf[i]       = W1[64 * 64 + i]  - W1[65 * 64 + i];
        wf[64 + i]  = W1[133 * 64 + i] - W1[132 * 64 + i];
        wf[128 + i] = W1[66 * 64 + i] - W1[67 * 64 + i]
                    - W1[134 * 64 + i] + W1[135 * 64 + i];
    }
    if (i < 4096) {
        int c = i >> 6, k = i & 63;
        W2tB[i] = f2b(W2[k * 64 + c]);
        W3tB[i] = f2b(W3[k * 64 + c]);
        float v = W1[k * 64 + c];
        short h = f2b(v);
        W1aT_hi[i] = h; W1aT_lo[i] = f2b(v - b2f(h));
        v = W1[(68 + k) * 64 + c];
        h = f2b(v);
        W1bT_hi[i] = h; W1bT_lo[i] = f2b(v - b2f(h));
    }
    if (i < 12288) {
        int c = i >> 6, k = i & 63;
        float v = Wih[(size_t)k * 192 + c];
        short h = f2b(v);
        WihT_hi[i] = h; WihT_lo[i] = f2b(v - b2f(h));
        v = Whh[(size_t)k * 192 + c];
        h = f2b(v);
        WhhT_hi[i] = h; WhhT_lo[i] = f2b(v - b2f(h));
    }
}

// init state/agg + CSR count (cnt zeroed in prep_all, which runs earlier on stream)
__global__ __launch_bounds__(256) void init_state(
    const float* __restrict__ b, const float* __restrict__ W_in,
    const float* __restrict__ b_in, const int* __restrict__ mn,
    float* __restrict__ state, float* __restrict__ agg0, float* __restrict__ agg1,
    int* __restrict__ cnt)
{
    int idx = blockIdx.x * 256 + threadIdx.x;
    if (idx >= NN * 64) return;
    int n = idx >> 6, j = idx & 63;
    state[idx] = b[n] * (W_in[j] - W_in[64 + j]) + b_in[j];
    agg0[idx] = 0.f;
    agg1[idx] = 0.f;
    if (idx < NE) atomicAdd(&cnt[mn[2 * idx + 1]], 1);
}

// ---------------- CSR scan + scatter ----------------
__global__ __launch_bounds__(256) void scan_block(const int* __restrict__ cnt,
                                                  int* __restrict__ base, int* __restrict__ bsum)
{
    __shared__ int s[256];
    int i = blockIdx.x * 256 + threadIdx.x;
    int v = (i < NN) ? cnt[i] : 0;
    s[threadIdx.x] = v;
    __syncthreads();
    for (int off = 1; off < 256; off <<= 1) {
        int t = (threadIdx.x >= off) ? s[threadIdx.x - off] : 0;
        __syncthreads();
        s[threadIdx.x] += t;
        __syncthreads();
    }
    if (i < NN) base[i] = s[threadIdx.x] - v;
    if (threadIdx.x == 255) bsum[blockIdx.x] = s[255];
}

__global__ __launch_bounds__(256) void scan_top(int* __restrict__ bsum, int nb)
{
    __shared__ int s[256];
    int t = threadIdx.x;
    int v = (t < nb) ? bsum[t] : 0;
    s[t] = v;
    __syncthreads();
    for (int off = 1; off < 256; off <<= 1) {
        int u = (t >= off) ? s[t - off] : 0;
        __syncthreads();
        s[t] += u;
        __syncthreads();
    }
    if (t < nb) bsum[t] = s[t] - v;
}

// AoS scatter: one 16B store per edge (ein, eout, J_bits, 0)
__global__ __launch_bounds__(256) void csr_scatter_perm(const int* __restrict__ mn,
    const float* __restrict__ Jm,
    const int* __restrict__ base, const int* __restrict__ bsum, int* __restrict__ cur,
    int4* __restrict__ edata)
{
    int e = blockIdx.x * 256 + threadIdx.x;
    if (e < NE) {
        int n = mn[2 * e + 1];
        int p = base[n] + bsum[n >> 8] + atomicAdd(&cur[n], 1);
        edata[p] = make_int4(mn[2 * e], n, __float_as_int(Jm[e]), 0);
    }
}

// ---------------- node_proj via MFMA (3-term split; weights in LDS) ----------------
__global__ __launch_bounds__(256, 4) void node_proj_mfma(
    const float* __restrict__ state, const float* __restrict__ bb,
    const short* __restrict__ W1aT_hi, const short* __restrict__ W1aT_lo,
    const short* __restrict__ W1bT_hi, const short* __restrict__ W1bT_lo,
    const float* __restrict__ wf, const float* __restrict__ b1,
    float* __restrict__ Pin, float* __restrict__ Pout)
{
    __shared__ float xh[64][68];
    __shared__ short wH[64][72];
    __shared__ short wL[64][72];
    __shared__ float sb[64];

    int tid = threadIdx.x;
    int wg = xcd_swz(blockIdx.x, gridDim.x);
    int ct = wg & 1;
    int n0 = (wg >> 1) * 64;

    const short* srcH = ct ? W1bT_hi : W1aT_hi;
    const short* srcL = ct ? W1bT_lo : W1aT_lo;
    float* P = ct ? Pout : Pin;

    {
        int row = tid >> 2, cb = (tid & 3) * 16;
        int n = n0 + row;
        bool ok = (n < NN);
#pragma unroll
        for (int q = 0; q < 4; q++) {
            float4 v = ok ? *(const float4*)&state[(size_t)n * 64 + cb + 4 * q]
                          : make_float4(0.f, 0.f, 0.f, 0.f);
            *(float4*)&xh[row][cb + 4 * q] = v;
        }
        *(bh8*)&wH[row][cb]     = *(const bh8*)&srcH[row * 64 + cb];
        *(bh8*)&wH[row][cb + 8] = *(const bh8*)&srcH[row * 64 + cb + 8];
        *(bh8*)&wL[row][cb]     = *(const bh8*)&srcL[row * 64 + cb];
        *(bh8*)&wL[row][cb + 8] = *(const bh8*)&srcL[row * 64 + cb + 8];
        if (tid < 64) sb[tid] = (n0 + tid < NN) ? bb[n0 + tid] : 0.f;
    }
    __syncthreads();

    int w = tid >> 6, l = tid & 63, lr = l & 15, lg = l >> 4;

    bh8 Sh1, Sl1, Sh2, Sl2;
    {
        float v[8];
        *(float4*)&v[0] = *(const float4*)&xh[16 * w + lr][8 * lg];
        *(float4*)&v[4] = *(const float4*)&xh[16 * w + lr][8 * lg + 4];
        split8(v, Sh1, Sl1);
        *(float4*)&v[0] = *(const float4*)&xh[16 * w + lr][8 * lg + 32];
        *(float4*)&v[4] = *(const float4*)&xh[16 * w + lr][8 * lg + 36];
        split8(v, Sh2, Sl2);
    }

#pragma unroll
    for (int c4 = 0; c4 < 4; c4++) {
        int brow = 16 * c4 + lr;
        bh8 Bh1 = *(const bh8*)&wH[brow][8 * lg];
        bh8 Bl1 = *(const bh8*)&wL[brow][8 * lg];
        bh8 Bh2 = *(const bh8*)&wH[brow][8 * lg + 32];
        bh8 Bl2 = *(const bh8*)&wL[brow][8 * lg + 32];
        fx4 acc = {0.f, 0.f, 0.f, 0.f};
        MFMA3(acc, Sh1, Sl1, Bh1, Bl1)
        MFMA3(acc, Sh2, Sl2, Bh2, Bl2)

        int c = 16 * c4 + lr;
        float F = wf[ct * 64 + c];
        float Bi = ct ? 0.f : b1[c];
#pragma unroll
        for (int r = 0; r < 4; r++) {
            int row = 16 * w + 4 * lg + r;
            int n = n0 + row;
            if (n < NN) P[(size_t)n * 64 + c] = acc[r] + sb[row] * F + Bi;
        }
    }
}

// ---------------- edge MLP + fused segment-sum (round-16 staging; 6 blocks/CU) ----------------
__global__ __launch_bounds__(256, 6) void edge_msg_mfma(
    const int4* __restrict__ edata,
    const float* __restrict__ Pin, const float* __restrict__ Pout,
    const float* __restrict__ wf,
    const short* __restrict__ W2tB, const float* __restrict__ b2,
    const short* __restrict__ W3tB, const float* __restrict__ b3,
    float* __restrict__ agg)
{
    __shared__ float h1f[64][68];   // h1, then h2 (band-private), then tband alias
    __shared__ short w23[64][72];   // W2^T, then restaged with W3^T
    __shared__ int   seo[64];

    float* tband = &h1f[0][0];      // 4*64 floats alias (h1f dead after GEMM3 reads)

    int tid = threadIdx.x;
    int wg = xcd_swz(blockIdx.x, gridDim.x);
    int p0 = wg * 64;

    int srow = tid >> 2, scb = (tid & 3) * 16;

    {   // stage: seo, h1 (lane=edge, quarter=wave), W2
        int m = tid & 63, kb = (tid >> 6) * 16;
        int4 ed = edata[p0 + m];
        int a = ed.x, o = ed.y;
        float J = __int_as_float(ed.z);
        if (tid < 64) seo[tid] = edata[p0 + tid].y;
#pragma unroll
        for (int q = 0; q < 4; q++) {
            float4 va = *(const float4*)&Pin[(size_t)a * 64 + kb + 4 * q];
            float4 vo = *(const float4*)&Pout[(size_t)o * 64 + kb + 4 * q];
            float4 vc = *(const float4*)&wf[128 + kb + 4 * q];
            float4 r;
            r.x = fmaxf(va.x + vo.x + J * vc.x, 0.f);
            r.y = fmaxf(va.y + vo.y + J * vc.y, 0.f);
            r.z = fmaxf(va.z + vo.z + J * vc.z, 0.f);
            r.w = fmaxf(va.w + vo.w + J * vc.w, 0.f);
            *(float4*)&h1f[m][kb + 4 * q] = r;
        }
        *(bh8*)&w23[srow][scb]     = *(const bh8*)&W2tB[srow * 64 + scb];
        *(bh8*)&w23[srow][scb + 8] = *(const bh8*)&W2tB[srow * 64 + scb + 8];
    }
    __syncthreads();

    int w = tid >> 6, l = tid & 63;
    int lr = l & 15, lg = l >> 4;

    float b2v[4], b3v[4];
#pragma unroll
    for (int ct = 0; ct < 4; ct++) { b2v[ct] = b2[ct * 16 + lr]; b3v[ct] = b3[ct * 16 + lr]; }

    // ---- GEMM2: h2 = relu(h1 @ W2 + b2); h2 -> h1f (own band) ----
    {
        float va[8], vb[8];
        *(float4*)&va[0] = *(const float4*)&h1f[16 * w + lr][lg * 8];
        *(float4*)&va[4] = *(const float4*)&h1f[16 * w + lr][lg * 8 + 4];
        *(float4*)&vb[0] = *(const float4*)&h1f[16 * w + lr][lg * 8 + 32];
        *(float4*)&vb[4] = *(const float4*)&h1f[16 * w + lr][lg * 8 + 36];
        bh8 Ahi1, Alo1, Ahi2, Alo2;
        split8(va, Ahi1, Alo1);
        split8(vb, Ahi2, Alo2);
#pragma unroll
        for (int ct = 0; ct < 4; ct++) {
            bh8 B1 = *(const bh8*)&w23[16 * ct + lr][lg * 8];
            bh8 B2 = *(const bh8*)&w23[16 * ct + lr][lg * 8 + 32];
            fx4 acc = {0.f, 0.f, 0.f, 0.f};
            acc = __builtin_amdgcn_mfma_f32_16x16x32_bf16(Ahi1, B1, acc, 0, 0, 0);
            acc = __builtin_amdgcn_mfma_f32_16x16x32_bf16(Alo1, B1, acc, 0, 0, 0);
            acc = __builtin_amdgcn_mfma_f32_16x16x32_bf16(Ahi2, B2, acc, 0, 0, 0);
            acc = __builtin_amdgcn_mfma_f32_16x16x32_bf16(Alo2, B2, acc, 0, 0, 0);
#pragma unroll
            for (int r = 0; r < 4; r++)
                h1f[16 * w + 4 * lg + r][16 * ct + lr] = fmaxf(acc[r] + b2v[ct], 0.f);
        }
    }
    __syncthreads();   // W2 reads done

    {   // restage w23 <- W3
        *(bh8*)&w23[srow][scb]     = *(const bh8*)&W3tB[srow * 64 + scb];
        *(bh8*)&w23[srow][scb + 8] = *(const bh8*)&W3tB[srow * 64 + scb + 8];
    }
    __syncthreads();

    // ---- GEMM3: m = h2 @ W3 + b3 -> registers ----
    fx4 macc[4];
    {
        float va[8], vb[8];
        *(float4*)&va[0] = *(const float4*)&h1f[16 * w + lr][lg * 8];
        *(float4*)&va[4] = *(const float4*)&h1f[16 * w + lr][lg * 8 + 4];
        *(float4*)&vb[0] = *(const float4*)&h1f[16 * w + lr][lg * 8 + 32];
        *(float4*)&vb[4] = *(const float4*)&h1f[16 * w + lr][lg * 8 + 36];
        bh8 Chi1, Clo1, Chi2, Clo2;
        split8(va, Chi1, Clo1);
        split8(vb, Chi2, Clo2);
#pragma unroll
        for (int ct = 0; ct < 4; ct++) {
            bh8 B1 = *(const bh8*)&w23[16 * ct + lr][lg * 8];
            bh8 B2 = *(const bh8*)&w23[16 * ct + lr][lg * 8 + 32];
            fx4 acc = {0.f, 0.f, 0.f, 0.f};
            acc = __builtin_amdgcn_mfma_f32_16x16x32_bf16(Chi1, B1, acc, 0, 0, 0);
            acc = __builtin_amdgcn_mfma_f32_16x16x32_bf16(Clo1, B1, acc, 0, 0, 0);
            acc = __builtin_amdgcn_mfma_f32_16x16x32_bf16(Chi2, B2, acc, 0, 0, 0);
            acc = __builtin_amdgcn_mfma_f32_16x16x32_bf16(Clo2, B2, acc, 0, 0, 0);
#pragma unroll
            for (int r = 0; r < 4; r++) acc[r] += b3v[ct];
            macc[ct] = acc;
        }
    }

    // ---- segmented scan ----
    int rowb = 16 * w + 4 * lg;
    int s0 = seo[rowb], s1 = seo[rowb + 1], s2 = seo[rowb + 2], s3 = seo[rowb + 3];

#pragma unroll
    for (int ct = 0; ct < 4; ct++) {
        if (s1 == s0) macc[ct][1] += macc[ct][0];
        if (s2 == s1) macc[ct][2] += macc[ct][1];
        if (s3 == s2) macc[ct][3] += macc[ct][2];
    }

    float c0[4], c1[4], c2[4];
#pragma unroll
    for (int ct = 0; ct < 4; ct++) {
        c0[ct] = __shfl(macc[ct][3], lr, 64);
        c1[ct] = __shfl(macc[ct][3], lr + 16, 64);
        c2[ct] = __shfl(macc[ct][3], lr + 32, 64);
    }
    {
        int k0 = seo[16 * w + 3], k1 = seo[16 * w + 7], k2 = seo[16 * w + 11];
        float cy[4] = {0.f, 0.f, 0.f, 0.f};
        bool m0 = (lg >= 1) && (k0 == s0);
        bool m1 = (lg >= 2) && (k1 == s0);
        bool m2 = (lg >= 3) && (k2 == s0);
#pragma unroll
        for (int ct = 0; ct < 4; ct++) {
            if (m0) cy[ct] += c0[ct];
            if (m1) cy[ct] += c1[ct];
            if (m2) cy[ct] += c2[ct];
        }
#pragma unroll
        for (int ct = 0; ct < 4; ct++) {
            macc[ct][0] += cy[ct];
            if (s1 == s0) macc[ct][1] += cy[ct];
            if (s2 == s0) macc[ct][2] += cy[ct];
            if (s3 == s0) macc[ct][3] += cy[ct];
        }
    }

    __syncthreads();   // all GEMM3 h1f reads done before tband (alias) writes
    if (lg == 3) {
#pragma unroll
        for (int ct = 0; ct < 4; ct++) tband[w * 64 + 16 * ct + lr] = macc[ct][3];
    }
    __syncthreads();
    {
        int bkey = seo[16 * w];
        int t0 = seo[15], t1 = seo[31], t2 = seo[47];
        float bc[4] = {0.f, 0.f, 0.f, 0.f};
        bool m0 = (w >= 1) && (t0 == bkey);
        bool m1 = (w >= 2) && (t1 == bkey);
        bool m2 = (w >= 3) && (t2 == bkey);
#pragma unroll
        for (int ct = 0; ct < 4; ct++) {
            if (m0) bc[ct] += tband[0 * 64 + 16 * ct + lr];
            if (m1) bc[ct] += tband[1 * 64 + 16 * ct + lr];
            if (m2) bc[ct] += tband[2 * 64 + 16 * ct + lr];
        }
#pragma unroll
        for (int ct = 0; ct < 4; ct++) {
            if (s0 == bkey) macc[ct][0] += bc[ct];
            if (s1 == bkey) macc[ct][1] += bc[ct];
            if (s2 == bkey) macc[ct][2] += bc[ct];
            if (s3 == bkey) macc[ct][3] += bc[ct];
        }
    }

    {   // emit tails
        int nh = seo[0], nt = seo[63];
        int sr[4] = { s0, s1, s2, s3 };
#pragma unroll
        for (int r = 0; r < 4; r++) {
            int p = rowb + r;
            int n = sr[r];
            bool tail = (p == 63) || (seo[p + 1] != n);
            if (tail) {
                float* ar = agg + (size_t)n * 64;
                if (n != nh && n != nt) {
                    ar[lr]      = macc[0][r];
                    ar[16 + lr] = macc[1][r];
                    ar[32 + lr] = macc[2][r];
                    ar[48 + lr] = macc[3][r];
                } else {
                    atomicAdd(&ar[lr],      macc[0][r]);
                    atomicAdd(&ar[16 + lr], macc[1][r]);
                    atomicAdd(&ar[32 + lr], macc[2][r]);
                    atomicAdd(&ar[48 + lr], macc[3][r]);
                }
            }
        }
    }
}

// ---------------- GRU via MFMA, q-split; A-frags direct from global; 5 blocks/CU ----------------
__global__ __launch_bounds__(256, 5) void gru_mfma(
    const float* __restrict__ agg, const float* __restrict__ state,
    const short* __restrict__ WihT_hi, const short* __restrict__ WihT_lo,
    const short* __restrict__ WhhT_hi, const short* __restrict__ WhhT_lo,
    const float* __restrict__ bih, const float* __restrict__ bhh,
    float* __restrict__ stateNext, float* __restrict__ aggNext)
{
    __shared__ short wiH[48][72];
    __shared__ short wiL[48][72];
    __shared__ short whH[48][72];
    __shared__ short whL[48][72];

    int tid = threadIdx.x;
    int wg = xcd_swz(blockIdx.x, gridDim.x);
    int tile = wg >> 2, q = wg & 3;
    int n0 = tile * 64;
    int w = tid >> 6, l = tid & 63, lr = l & 15, lg = l >> 4;

    int arow = 16 * w + lr;
    size_t abase = (size_t)(n0 + arow) * 64;

    bh8 Agh1, Agl1, Agh2, Agl2, Ash1, Asl1, Ash2, Asl2;
    {
        float v[8];
        *(float4*)&v[0] = *(const float4*)&agg[abase + 8 * lg];
        *(float4*)&v[4] = *(const float4*)&agg[abase + 8 * lg + 4];
        split8(v, Agh1, Agl1);
        *(float4*)&v[0] = *(const float4*)&agg[abase + 8 * lg + 32];
        *(float4*)&v[4] = *(const float4*)&agg[abase + 8 * lg + 36];
        split8(v, Agh2, Agl2);
        *(float4*)&v[0] = *(const float4*)&state[abase + 8 * lg];
        *(float4*)&v[4] = *(const float4*)&state[abase + 8 * lg + 4];
        split8(v, Ash1, Asl1);
        *(float4*)&v[0] = *(const float4*)&state[abase + 8 * lg + 32];
        *(float4*)&v[4] = *(const float4*)&state[abase + 8 * lg + 36];
        split8(v, Ash2, Asl2);
    }

    {   // stage weights + zero aggNext (q==0)
        const short* src = (w == 0) ? WihT_hi : (w == 1) ? WihT_lo
                         : (w == 2) ? WhhT_hi : WhhT_lo;
        short (*dst)[72] = (w == 0) ? wiH : (w == 1) ? wiL : (w == 2) ? whH : whL;
#pragma unroll
        for (int it = 0; it < 6; it++) {
            int idx = it * 64 + l;
            int row2 = idx >> 3, ch = idx & 7;
            int g = row2 >> 4, i = row2 & 15;
            int gcol = g * 64 + q * 16 + i;
            *(bh8*)&dst[row2][ch * 8] = *(const bh8*)&src[(size_t)gcol * 64 + ch * 8];
        }
        if (q == 0) {
            int row = tid >> 2, cb = (tid & 3) * 16;
            int n = n0 + row;
            if (n < NN) {
#pragma unroll
                for (int qq = 0; qq < 4; qq++)
                    *(float4*)&aggNext[(size_t)n * 64 + cb + 4 * qq] =
                        make_float4(0.f, 0.f, 0.f, 0.f);
            }
        }
    }
    __syncthreads();

    fx4 giT[3], ghT[3];
#pragma unroll
    for (int g = 0; g < 3; g++) {
        int brow = g * 16 + lr;
        {
            bh8 Bh1 = *(const bh8*)&wiH[brow][8 * lg];
            bh8 Bl1 = *(const bh8*)&wiL[brow][8 * lg];
            bh8 Bh2 = *(const bh8*)&wiH[brow][8 * lg + 32];
            bh8 Bl2 = *(const bh8*)&wiL[brow][8 * lg + 32];
            fx4 acc = {0.f, 0.f, 0.f, 0.f};
            MFMA3(acc, Agh1, Agl1, Bh1, Bl1)
            MFMA3(acc, Agh2, Agl2, Bh2, Bl2)
            giT[g] = acc;
        }
        {
            bh8 Bh1 = *(const bh8*)&whH[brow][8 * lg];
            bh8 Bl1 = *(const bh8*)&whL[brow][8 * lg];
            bh8 Bh2 = *(const bh8*)&whH[brow][8 * lg + 32];
            bh8 Bl2 = *(const bh8*)&whL[brow][8 * lg + 32];
            fx4 acc = {0.f, 0.f, 0.f, 0.f};
            MFMA3(acc, Ash1, Asl1, Bh1, Bl1)
            MFMA3(acc, Ash2, Asl2, Bh2, Bl2)
            ghT[g] = acc;
        }
    }

    {
        int c = q * 16 + lr;
        float bir = bih[c], biz = bih[64 + c], bin = bih[128 + c];
        float bhr = bhh[c], bhz = bhh[64 + c], bhn = bhh[128 + c];
#pragma unroll
        for (int r = 0; r < 4; r++) {
            int row = 16 * w + 4 * lg + r;
            int n = n0 + row;
            if (n < NN) {
                float rg = sigm(giT[0][r] + bir + ghT[0][r] + bhr);
                float zg = sigm(giT[1][r] + biz + ghT[1][r] + bhz);
                float ng = tanhf(giT[2][r] + bin + rg * (ghT[2][r] + bhn));
                float hold = state[(size_t)n * 64 + c];
                stateNext[(size_t)n * 64 + c] = (1.f - zg) * ng + zg * hold;
            }
        }
    }
}

__global__ __launch_bounds__(256) void out_proj(
    const float* __restrict__ state, const float* __restrict__ Wout,
    const float* __restrict__ bout, float* __restrict__ out)
{
    int n = blockIdx.x * 256 + threadIdx.x;
    if (n >= NN) return;
    float a0 = bout[0], a1 = bout[1];
    const float4* sr = (const float4*)(state + (size_t)n * 64);
#pragma unroll
    for (int t = 0; t < 16; t++) {
        float4 v = sr[t];
        a0 += v.x * Wout[2 * (4 * t + 0)] + v.y * Wout[2 * (4 * t + 1)]
            + v.z * Wout[2 * (4 * t + 2)] + v.w * Wout[2 * (4 * t + 3)];
        a1 += v.x * Wout[2 * (4 * t + 0) + 1] + v.y * Wout[2 * (4 * t + 1) + 1]
            + v.z * Wout[2 * (4 * t + 2) + 1] + v.w * Wout[2 * (4 * t + 3) + 1];
    }
    out[2 * n] = a0;
    out[2 * n + 1] = a1;
}

extern "C" void kernel_launch(void* const* d_in, const int* in_sizes, int n_in,
                              void* d_out, int out_size, void* d_ws, size_t ws_size,
                              hipStream_t stream)
{
    const int*   msg_node = (const int*)  d_in[0];
    const float* J_msg    = (const float*)d_in[1];
    const float* b        = (const float*)d_in[2];
    const float* W_in     = (const float*)d_in[4];
    const float* b_in     = (const float*)d_in[5];
    const float* W1       = (const float*)d_in[6];
    const float* b1       = (const float*)d_in[7];
    const float* W2       = (const float*)d_in[8];
    const float* b2       = (const float*)d_in[9];
    const float* W3       = (const float*)d_in[10];
    const float* b3       = (const float*)d_in[11];
    const float* W_ih     = (const float*)d_in[12];
    const float* b_ih     = (const float*)d_in[13];
    const float* W_hh     = (const float*)d_in[14];
    const float* b_hh     = (const float*)d_in[15];
    const float* W_out    = (const float*)d_in[16];
    const float* b_out    = (const float*)d_in[17];

    float* f      = (float*)d_ws;
    float* state0 = f;                                  // NN*64
    float* state1 = state0 + (size_t)NN * 64;           // NN*64
    float* agg0   = state1 + (size_t)NN * 64;           // NN*64
    float* agg1   = agg0   + (size_t)NN * 64;           // NN*64
    float* Pin    = agg1   + (size_t)NN * 64;           // NN*64
    float* Pout   = Pin    + (size_t)NN * 64;           // NN*64
    float* wf     = Pout   + (size_t)NN * 64;           // 192
    int*   cbase  = (int*)(wf + 192);                   // NN
    int*   ccnt   = cbase + NN;                         // NN
    int*   ccur   = ccnt + NN;                          // NN
    int*   cbsum  = ccur + NN;                          // 512
    short* W2tB   = (short*)(cbsum + 512);              // 4096
    short* W3tB   = W2tB + 4096;                        // 4096
    short* WihT_hi = W3tB + 4096;                       // 12288
    short* WihT_lo = WihT_hi + 12288;
    short* WhhT_hi = WihT_lo + 12288;
    short* WhhT_lo = WhhT_hi + 12288;
    short* W1aT_hi = WhhT_lo + 12288;                   // 4096
    short* W1aT_lo = W1aT_hi + 4096;
    short* W1bT_hi = W1aT_lo + 4096;
    short* W1bT_lo = W1bT_hi + 4096;
    size_t off = ((size_t)((char*)(W1bT_lo + 4096) - (char*)d_ws) + 15) & ~(size_t)15;
    int4*  edata = (int4*)((char*)d_ws + off);          // NE int4

    float* stateBuf[2] = { state0, state1 };
    float* aggBuf[2]   = { agg0, agg1 };
    float* out = (float*)d_out;

    prep_all<<<(NN + 255) / 256, 256, 0, stream>>>(W1, W2, W3, W_ih, W_hh, wf,
                                                   W2tB, W3tB,
                                                   WihT_hi, WihT_lo, WhhT_hi, WhhT_lo,
                                                   W1aT_hi, W1aT_lo, W1bT_hi, W1bT_lo,
                                                   ccnt, ccur);
    init_state<<<(NN * 64 + 255) / 256, 256, 0, stream>>>(b, W_in, b_in, msg_node,
                                                          state0, agg0, agg1, ccnt);

    scan_block<<<(NN + 255) / 256, 256, 0, stream>>>(ccnt, cbase, cbsum);
    scan_top<<<1, 256, 0, stream>>>(cbsum, (NN + 255) / 256);
    csr_scatter_perm<<<(NE + 255) / 256, 256, 0, stream>>>(msg_node, J_msg,
                                                           cbase, cbsum, ccur,
                                                           edata);

    int ntile = (NN + 63) / 64;
    for (int p = 0; p < 3; p++) {
        float* sc = stateBuf[p & 1];
        float* sn = stateBuf[(p + 1) & 1];
        float* ac = aggBuf[p & 1];
        float* an = aggBuf[(p + 1) & 1];
        node_proj_mfma<<<ntile * 2, 256, 0, stream>>>(sc, b,
                                                      W1aT_hi, W1aT_lo, W1bT_hi, W1bT_lo,
                                                      wf, b1, Pin, Pout);
        edge_msg_mfma<<<NE / 64, 256, 0, stream>>>(edata, Pin, Pout, wf,
                                                   W2tB, b2, W3tB, b3, ac);
        gru_mfma<<<ntile * 4, 256, 0, stream>>>(ac, sc,
                                                WihT_hi, WihT_lo, WhhT_hi, WhhT_lo,
                                                b_ih, b_hh, sn, an);
    }
    out_proj<<<(NN + 255) / 256, 256, 0, stream>>>(stateBuf[1], W_out, b_out, out);
}